// Round 2
// 3022.069 us; speedup vs baseline: 1.5362x; 1.5362x over previous
//
#include <hip/hip_runtime.h>
#include <stdint.h>

typedef unsigned short u16;
typedef __attribute__((ext_vector_type(8))) short short8;     // 8 bf16 (MFMA A/B frag)
typedef __attribute__((ext_vector_type(4))) float float4_;    // MFMA C/D frag

#define NB 8
#define LL 4096
#define DD 1024
#define CC 64
#define NCH 64   // LL/CC

__device__ __forceinline__ u16 f2bf(float f) {
  union { float f; uint32_t u; } v; v.f = f;
  uint32_t u = v.u;
  return (u16)((u + 0x7fffu + ((u >> 16) & 1u)) >> 16);   // RNE
}
__device__ __forceinline__ float bf2f(u16 h) {
  union { uint32_t u; float f; } v; v.u = ((uint32_t)h) << 16;
  return v.f;
}
__device__ __forceinline__ float4_ mfma16(short8 a, short8 b, float4_ c) {
  return __builtin_amdgcn_mfma_f32_16x16x32_bf16(a, b, c, 0, 0, 0);
}

// ---------------- dtype detect: flag=1 if inputs are bf16, 0 if f32 ----------------
__global__ void k_detect(const uint32_t* __restrict__ X, int* __restrict__ flag) {
  if (threadIdx.x == 0 && blockIdx.x == 0) {
    int votes = 0;
    for (int i = 0; i < 64; ++i) {
      uint32_t w = X[i];
      uint32_t e = (w >> 7) & 0xFF;   // exponent field of the LOW u16 viewed as bf16
      votes += (e > 134 || e < 110) ? 1 : 0;
    }
    *flag = (votes < 8) ? 1 : 0;
  }
}

// ---------------- convert input tensor -> bf16 (dual dtype) ----------------
__global__ __launch_bounds__(256) void k_convert(const void* __restrict__ src, u16* __restrict__ dst,
                                                 long n8, const int* __restrict__ flag) {
  long i = (long)blockIdx.x * 256 + threadIdx.x;   // index of 8-element chunk
  if (i >= n8) return;
  if (*flag) {
    ((short8*)dst)[i] = ((const short8*)src)[i];
  } else {
    const float4_* s = (const float4_*)src;
    float4_ a = s[2 * i], b = s[2 * i + 1];
    short8 o;
#pragma unroll
    for (int j = 0; j < 4; ++j) { o[j] = (short)f2bf(a[j]); o[4 + j] = (short)f2bf(b[j]); }
    ((short8*)dst)[i] = o;
  }
}

// ---------------- big NT GEMM: Out(M x 1024) = A(M x 1024) @ W(1024 x 1024)^T + bias ----------------
template <bool DUAL>
__device__ __forceinline__ void gemm128(const u16* __restrict__ A, const u16* __restrict__ W,
                                        const u16* __restrict__ bias, void* __restrict__ Out,
                                        int m0, int n0, const int* __restrict__ flag) {
  __shared__ __attribute__((aligned(16))) u16 As[128 * 64];
  __shared__ __attribute__((aligned(16))) u16 Bs[128 * 64];
  const int tid = threadIdx.x, lane = tid & 63, wv = tid >> 6;
  float4_ acc[2][8];
#pragma unroll
  for (int i = 0; i < 2; ++i)
#pragma unroll
    for (int j = 0; j < 8; ++j) acc[i][j] = (float4_)0.f;

  for (int kk = 0; kk < DD; kk += 64) {
#pragma unroll
    for (int i = 0; i < 4; ++i) {
      int e = tid + 256 * i;
      int row = e >> 3, col = (e & 7) * 8;
      *(short8*)&As[row * 64 + col] = *(const short8*)(A + (size_t)(m0 + row) * DD + kk + col);
      *(short8*)&Bs[row * 64 + col] = *(const short8*)(W + (size_t)(n0 + row) * DD + kk + col);
    }
    __syncthreads();
#pragma unroll
    for (int ks = 0; ks < 2; ++ks) {
      short8 af[2];
#pragma unroll
      for (int mt = 0; mt < 2; ++mt)
        af[mt] = *(const short8*)&As[(32 * wv + 16 * mt + (lane & 15)) * 64 + ks * 32 + (lane >> 4) * 8];
#pragma unroll
      for (int nt = 0; nt < 8; ++nt) {
        short8 bf = *(const short8*)&Bs[(16 * nt + (lane & 15)) * 64 + ks * 32 + (lane >> 4) * 8];
#pragma unroll
        for (int mt = 0; mt < 2; ++mt) acc[mt][nt] = mfma16(af[mt], bf, acc[mt][nt]);
      }
    }
    __syncthreads();
  }
  const bool obf = DUAL ? (*flag != 0) : true;
#pragma unroll
  for (int mt = 0; mt < 2; ++mt)
#pragma unroll
    for (int nt = 0; nt < 8; ++nt) {
      int rg = m0 + 32 * wv + 16 * mt + ((lane >> 4) << 2);
      int cg = n0 + 16 * nt + (lane & 15);
      float bv = bf2f(bias[cg]);
#pragma unroll
      for (int r = 0; r < 4; ++r) {
        float o = acc[mt][nt][r] + bv;
        if (obf) ((u16*)Out)[(size_t)(rg + r) * DD + cg] = f2bf(o);
        else     ((float*)Out)[(size_t)(rg + r) * DD + cg] = o;
      }
    }
}

__global__ __launch_bounds__(256) void k_gemm_qkv(const u16* __restrict__ X,
    const u16* __restrict__ Wq, const u16* __restrict__ bq,
    const u16* __restrict__ Wk, const u16* __restrict__ bk,
    const u16* __restrict__ Wv, const u16* __restrict__ bv,
    u16* __restrict__ Qo, u16* __restrict__ Ko, u16* __restrict__ Vo) {
  int nb = blockIdx.x;  // 0..23
  int mat = nb >> 3, nt = nb & 7;
  const u16 *W, *bi; u16* O;
  if (mat == 0)      { W = Wq; bi = bq; O = Qo; }
  else if (mat == 1) { W = Wk; bi = bk; O = Ko; }
  else               { W = Wv; bi = bv; O = Vo; }
  gemm128<false>(X, W, bi, O, blockIdx.y * 128, nt * 128, nullptr);
}

__global__ __launch_bounds__(256) void k_gemm_o(const u16* __restrict__ A,
    const u16* __restrict__ Wo, const u16* __restrict__ bo, void* __restrict__ Out,
    const int* __restrict__ flag) {
  gemm128<true>(A, Wo, bo, Out, blockIdx.y * 128, blockIdx.x * 128, flag);
}

// ---------------- prep: per (chunk, batch): beta, T2, U0 (over V), A=tril(QK^T),
//                  W = T2@K (ALL chunks) -> Wall, and K^T emission -> KTg (B,D,L) ----------------
__global__ __launch_bounds__(256) void k_prep(const u16* __restrict__ Q, const u16* __restrict__ K,
                                              u16* __restrict__ V /* V in, U0 out (in place) */,
                                              u16* __restrict__ Aout, u16* __restrict__ Wall,
                                              u16* __restrict__ KTg) {
  const int ch = blockIdx.x, b = blockIdx.y;
  const size_t row0 = (size_t)b * LL + (size_t)ch * CC;
  const int tid = threadIdx.x, lane = tid & 63, wv = tid >> 6;

  __shared__ __attribute__((aligned(16))) float Gs[64 * 65];   // reused as KTs (u16 64x72) in phase B
  __shared__ __attribute__((aligned(16))) float Ts[64 * 65];   // reused as VTs (u16 64x72) in phase B
  __shared__ __attribute__((aligned(16))) u16 Kt[64 * 64];
  __shared__ __attribute__((aligned(16))) u16 Qt[64 * 64];
  __shared__ __attribute__((aligned(16))) u16 T2s[64 * 72];
  __shared__ float betas[64];

  float4_ accG[4], accA[4];
#pragma unroll
  for (int ct = 0; ct < 4; ++ct) { accG[ct] = (float4_)0.f; accA[ct] = (float4_)0.f; }

  // phase A: G = K K^T, Araw = Q K^T  (K-streamed)
  for (int kk = 0; kk < DD; kk += 64) {
#pragma unroll
    for (int i = 0; i < 2; ++i) {
      int e = tid + 256 * i;
      int row = e >> 3, col = (e & 7) * 8;
      *(short8*)&Kt[row * 64 + col] = *(const short8*)(K + (row0 + row) * DD + kk + col);
      *(short8*)&Qt[row * 64 + col] = *(const short8*)(Q + (row0 + row) * DD + kk + col);
    }
    __syncthreads();
#pragma unroll
    for (int ks = 0; ks < 2; ++ks) {
      short8 ak = *(const short8*)&Kt[(16 * wv + (lane & 15)) * 64 + ks * 32 + (lane >> 4) * 8];
      short8 aq = *(const short8*)&Qt[(16 * wv + (lane & 15)) * 64 + ks * 32 + (lane >> 4) * 8];
#pragma unroll
      for (int ct = 0; ct < 4; ++ct) {
        short8 bk = *(const short8*)&Kt[(16 * ct + (lane & 15)) * 64 + ks * 32 + (lane >> 4) * 8];
        accG[ct] = mfma16(ak, bk, accG[ct]);
        accA[ct] = mfma16(aq, bk, accA[ct]);
      }
    }
    __syncthreads();
  }
  u16* Abase = Aout + (size_t)(b * NCH + ch) * (CC * CC);
#pragma unroll
  for (int ct = 0; ct < 4; ++ct) {
    int i0 = 16 * wv + ((lane >> 4) << 2);
    int c = 16 * ct + (lane & 15);
#pragma unroll
    for (int r = 0; r < 4; ++r) {
      int i = i0 + r;
      Gs[i * 65 + c] = accG[ct][r];
      Abase[i * 64 + c] = f2bf((c <= i) ? accA[ct][r] : 0.f);
    }
  }
  __syncthreads();
  if (tid < 64) betas[tid] = 1.f / (Gs[tid * 65 + tid] + 1e-6f);
  __syncthreads();
  for (int e = tid; e < 4096; e += 256) {
    int i = e >> 6, c = e & 63;
    Ts[i * 65 + c] = (c < i) ? (-betas[i] * Gs[i * 65 + c]) : 0.f;
  }
  __syncthreads();
  // forward substitution (reference exact recurrence)
  for (int i = 1; i < 64; ++i) {
    float rv = 0.f, acc = 0.f;
    if (tid < 64) {
      rv = Ts[i * 65 + tid];
      for (int j = 1; j < i; ++j) {
        float a = __shfl(rv, j);
        acc += a * Ts[j * 65 + tid];
      }
    }
    __syncthreads();
    if (tid < i) Ts[i * 65 + tid] = rv + acc;
    __syncthreads();
  }
  if (tid < 64) Ts[tid * 65 + tid] += 1.f;
  __syncthreads();
  for (int e = tid; e < 4096; e += 256) {   // T2[i][j] = T[i][j]*beta[j] (LDS only)
    int i = e >> 6, j = e & 63;
    T2s[i * 72 + j] = f2bf(Ts[i * 65 + j] * betas[j]);
  }
  __syncthreads();

  // phase B: U0 = T2 @ V (over V); W = T2 @ K -> Wall (all chunks); emit K^T -> KTg
  u16* KTs = (u16*)Gs;  // 64 x 72
  u16* VTs = (u16*)Ts;  // 64 x 72
  for (int kk = 0; kk < DD; kk += 64) {
#pragma unroll
    for (int rep = 0; rep < 2; ++rep) {   // transpose V and K tiles into LDS
      int t = tid >> 2;
      int c0 = (tid & 3) * 8 + rep * 32;
      short8 vv = *(const short8*)(V + (row0 + t) * DD + kk + c0);
      short8 vk = *(const short8*)(K + (row0 + t) * DD + kk + c0);
#pragma unroll
      for (int e = 0; e < 8; ++e) { VTs[(c0 + e) * 72 + t] = (u16)vv[e]; KTs[(c0 + e) * 72 + t] = (u16)vk[e]; }
    }
    __syncthreads();
    // emit K^T tile to global: KTg[(b, kk+jl, ch*64 + t)]
#pragma unroll
    for (int w2 = 0; w2 < 2; ++w2) {
      int e = tid + 256 * w2;
      int jl = e >> 3, toff = (e & 7) * 8;
      *(short8*)(KTg + ((size_t)b * DD + kk + jl) * LL + (size_t)ch * CC + toff) =
          *(const short8*)&KTs[jl * 72 + toff];
    }
    float4_ accU[4], accW[4];
#pragma unroll
    for (int ct = 0; ct < 4; ++ct) { accU[ct] = (float4_)0.f; accW[ct] = (float4_)0.f; }
#pragma unroll
    for (int ks = 0; ks < 2; ++ks) {
      short8 a2 = *(const short8*)&T2s[(16 * wv + (lane & 15)) * 72 + ks * 32 + (lane >> 4) * 8];
#pragma unroll
      for (int ct = 0; ct < 4; ++ct) {
        short8 bu = *(const short8*)&VTs[(16 * ct + (lane & 15)) * 72 + ks * 32 + (lane >> 4) * 8];
        short8 bw = *(const short8*)&KTs[(16 * ct + (lane & 15)) * 72 + ks * 32 + (lane >> 4) * 8];
        accU[ct] = mfma16(a2, bu, accU[ct]);
        accW[ct] = mfma16(a2, bw, accW[ct]);
      }
    }
#pragma unroll
    for (int ct = 0; ct < 4; ++ct) {
      int i0 = 16 * wv + ((lane >> 4) << 2);
      int c = kk + 16 * ct + (lane & 15);
#pragma unroll
      for (int r = 0; r < 4; ++r) {
        V[(row0 + i0 + r) * DD + c]    = f2bf(accU[ct][r]);   // U0 over V
        Wall[(row0 + i0 + r) * DD + c] = f2bf(accW[ct][r]);   // W for all chunks
      }
    }
    __syncthreads();
  }
}

// ---------------- fused scan: one persistent workgroup per (b, 32-col slice of d_v) ----------------
// S^T[32][1028] f32 lives in (static) LDS across all 64 chunks. No inter-workgroup communication.
// per chunk: u = U0 - W@S, oq = Q@S (k-split across waves, f32 LDS atomic reduce),
//            o = A@u + oq -> Og,   S += K^T@u (wave-split by dj, b128 RMW on LDS).
__global__ __launch_bounds__(256, 1) void k_scan_fused(
    const u16* __restrict__ Q, const u16* __restrict__ Wg, const u16* __restrict__ KTg,
    const u16* __restrict__ U0, const u16* __restrict__ Ag, u16* __restrict__ Og) {
  __shared__ __attribute__((aligned(16))) float S[32 * 1028];     // 131584 B
  __shared__ __attribute__((aligned(16))) float u_acc[64 * 33];   //   8448 B
  __shared__ __attribute__((aligned(16))) float oq_acc[64 * 33];  //   8448 B
  __shared__ __attribute__((aligned(16))) u16 uT[32 * 72];        //   4608 B  -> 153088 total

  const int b = blockIdx.x & 7;               // XCD-affinity: batch b -> XCD b
  const int dc0 = (blockIdx.x >> 3) * 32;
  const int tid = threadIdx.x, lane = tid & 63, wv = tid >> 6;
  const int r15 = lane & 15, hi = lane >> 4;  // hi in 0..3
  const int khi = hi * 8;
  const int tI = tid >> 2, cI = (tid & 3) * 8;

  for (int i = tid; i < 32 * 1028; i += 256) S[i] = 0.f;
  __syncthreads();

  for (int ch = 0; ch < NCH; ++ch) {
    const size_t row0 = (size_t)b * LL + (size_t)ch * CC;
    // ---- init: u_acc = U0 (f32), oq_acc = 0
    {
      short8 v = *(const short8*)(U0 + (row0 + tI) * DD + dc0 + cI);
#pragma unroll
      for (int e = 0; e < 8; ++e) {
        u_acc[tI * 33 + cI + e]  = bf2f((u16)v[e]);
        oq_acc[tI * 33 + cI + e] = 0.f;
      }
    }
    __syncthreads();
    // ---- phase 1: wave wv covers j in [256*wv, 256*wv+256)
    {
      float4_ up[4][2], qp[4][2];
#pragma unroll
      for (int tt = 0; tt < 4; ++tt)
#pragma unroll
        for (int dt = 0; dt < 2; ++dt) { up[tt][dt] = (float4_)0.f; qp[tt][dt] = (float4_)0.f; }
#pragma unroll 2
      for (int ks = 0; ks < 8; ++ks) {
        const int j0 = wv * 256 + ks * 32 + khi;
        short8 sf[2];
#pragma unroll
        for (int dt = 0; dt < 2; ++dt) {
          const float* sp = &S[(dt * 16 + r15) * 1028 + j0];
          float4_ x0 = *(const float4_*)sp;
          float4_ x1 = *(const float4_*)(sp + 4);
          short8 s;
#pragma unroll
          for (int e = 0; e < 4; ++e) { s[e] = (short)f2bf(x0[e]); s[4 + e] = (short)f2bf(x1[e]); }
          sf[dt] = s;
        }
#pragma unroll
        for (int tt = 0; tt < 4; ++tt) {
          const size_t rbase = (row0 + tt * 16 + r15) * DD + j0;
          short8 wf = *(const short8*)(Wg + rbase);
          short8 qf = *(const short8*)(Q + rbase);
#pragma unroll
          for (int dt = 0; dt < 2; ++dt) {
            up[tt][dt] = mfma16(wf, sf[dt], up[tt][dt]);
            qp[tt][dt] = mfma16(qf, sf[dt], qp[tt][dt]);
          }
        }
      }
#pragma unroll
      for (int tt = 0; tt < 4; ++tt)
#pragma unroll
        for (int dt = 0; dt < 2; ++dt) {
          const int t0 = tt * 16 + hi * 4, dc = dt * 16 + r15;
#pragma unroll
          for (int r = 0; r < 4; ++r) {
            atomicAdd(&u_acc[(t0 + r) * 33 + dc], -up[tt][dt][r]);
            atomicAdd(&oq_acc[(t0 + r) * 33 + dc], qp[tt][dt][r]);
          }
        }
    }
    __syncthreads();
    // ---- build uT bf16 [dc][t]
    {
      const float* pu = &u_acc[tI * 33 + cI];
#pragma unroll
      for (int e = 0; e < 8; ++e) uT[(cI + e) * 72 + tI] = f2bf(pu[e]);
    }
    __syncthreads();
    {
      short8 ub[2][2];   // uT B-frags, shared by phases 3 and 4
#pragma unroll
      for (int dt = 0; dt < 2; ++dt)
#pragma unroll
        for (int ks = 0; ks < 2; ++ks)
          ub[dt][ks] = *(const short8*)&uT[(dt * 16 + r15) * 72 + ks * 32 + khi];
      // ---- phase 3: S[dc][dj] += sum_t u[t,dc] K[t,dj], wave wv's dj slice (out tile = (dj, dc))
      const size_t ktb = ((size_t)b * DD) * LL + (size_t)ch * CC;
#pragma unroll 4
      for (int djt = 0; djt < 16; ++djt) {
        const int dj0 = wv * 256 + djt * 16;
        short8 kf0 = *(const short8*)(KTg + ktb + (size_t)(dj0 + r15) * LL + khi);
        short8 kf1 = *(const short8*)(KTg + ktb + (size_t)(dj0 + r15) * LL + 32 + khi);
#pragma unroll
        for (int dt = 0; dt < 2; ++dt) {
          float* sp = &S[(dt * 16 + r15) * 1028 + dj0 + hi * 4];
          float4_ c = *(const float4_*)sp;
          c = mfma16(kf0, ub[dt][0], c);
          c = mfma16(kf1, ub[dt][1], c);
          *(float4_*)sp = c;
        }
      }
      // ---- phase 4: o = A@u + oq -> Og (wave wv -> t-tile wv)
      const u16* Ab = Ag + (size_t)(b * NCH + ch) * (CC * CC);
      short8 af0 = *(const short8*)(Ab + (wv * 16 + r15) * CC + khi);
      short8 af1 = *(const short8*)(Ab + (wv * 16 + r15) * CC + 32 + khi);
      const int t0 = wv * 16 + hi * 4;
#pragma unroll
      for (int dt = 0; dt < 2; ++dt) {
        const int dc = dt * 16 + r15;
        float4_ c;
#pragma unroll
        for (int r = 0; r < 4; ++r) c[r] = oq_acc[(t0 + r) * 33 + dc];
        c = mfma16(af0, ub[dt][0], c);
        c = mfma16(af1, ub[dt][1], c);
#pragma unroll
        for (int r = 0; r < 4; ++r)
          Og[(row0 + t0 + r) * DD + dc0 + dc] = f2bf(c[r]);
      }
    }
    __syncthreads();
  }
}

extern "C" void kernel_launch(void* const* d_in, const int* in_sizes, int n_in,
                              void* d_out, int out_size, void* d_ws, size_t ws_size,
                              hipStream_t stream) {
  (void)in_sizes; (void)n_in; (void)out_size; (void)ws_size;
  const void* X  = d_in[0];
  // d_in[1] = chunk (=64), hard-coded
  const void* Wq = d_in[2]; const void* bq = d_in[3];
  const void* Wk = d_in[4]; const void* bk = d_in[5];
  const void* Wv = d_in[6]; const void* bv = d_in[7];
  const void* Wo = d_in[8]; const void* bo = d_in[9];

  char* ws = (char*)d_ws;
  int* flag = (int*)ws;
  char* p = ws + 256;
  const size_t E2 = (size_t)NB * LL * DD * 2;                  // 64 MiB per bf16 (B,L,D)
  u16* xb   = (u16*)p; p += E2;                                // X bf16; K^T (B,D,L) overlays after QKV
  u16* kt   = xb;
  u16* wqb  = (u16*)p; p += (size_t)DD * DD * 2;
  u16* wkb  = (u16*)p; p += (size_t)DD * DD * 2;
  u16* wvb  = (u16*)p; p += (size_t)DD * DD * 2;
  u16* wob  = (u16*)p; p += (size_t)DD * DD * 2;
  u16* bqb  = (u16*)p; p += 4096;
  u16* bkb  = (u16*)p; p += 4096;
  u16* bvb  = (u16*)p; p += 4096;
  u16* bob  = (u16*)p; p += 4096;
  u16* q_ws = (u16*)p; p += E2;                                // Q
  u16* k_ws = (u16*)p; p += E2;                                // K; scan writes o (Opre) here
  u16* v_ws = (u16*)p; p += E2;                                // V -> U0 in place
  u16* a_ws = (u16*)p; p += (size_t)NB * NCH * CC * CC * 2;    // 4 MiB
  u16* w_all = (u16*)p; p += E2;                               // W = T2@K for all chunks
  // total ~268 MiB

  k_detect<<<1, 64, 0, stream>>>((const uint32_t*)X, flag);
  const long nX = (long)NB * LL * DD / 8;
  k_convert<<<(nX + 255) / 256, 256, 0, stream>>>(X, xb, nX, flag);
  const long nW = (long)DD * DD / 8;
  k_convert<<<(nW + 255) / 256, 256, 0, stream>>>(Wq, wqb, nW, flag);
  k_convert<<<(nW + 255) / 256, 256, 0, stream>>>(Wk, wkb, nW, flag);
  k_convert<<<(nW + 255) / 256, 256, 0, stream>>>(Wv, wvb, nW, flag);
  k_convert<<<(nW + 255) / 256, 256, 0, stream>>>(Wo, wob, nW, flag);
  const long nBias = DD / 8;
  k_convert<<<1, 256, 0, stream>>>(bq, bqb, nBias, flag);
  k_convert<<<1, 256, 0, stream>>>(bk, bkb, nBias, flag);
  k_convert<<<1, 256, 0, stream>>>(bv, bvb, nBias, flag);
  k_convert<<<1, 256, 0, stream>>>(bo, bob, nBias, flag);

  k_gemm_qkv<<<dim3(24, 256), 256, 0, stream>>>(xb, wqb, bqb, wkb, bkb, wvb, bvb, q_ws, k_ws, v_ws);
  k_prep<<<dim3(64, 8), 256, 0, stream>>>(q_ws, k_ws, v_ws, a_ws, w_all, kt);
  k_scan_fused<<<dim3(256), 256, 0, stream>>>(q_ws, w_all, kt, v_ws, a_ws, k_ws);
  k_gemm_o<<<dim3(8, 256), 256, 0, stream>>>(k_ws, wob, bob, d_out, flag);
}